// Round 1
// baseline (1847.858 us; speedup 1.0000x reference)
//
#include <hip/hip_runtime.h>

// Problem constants (from reference)
#define N0s 200000
#define N1s 50000
#define N2s 12500
#define N3s 3200
#define E0s 500000
#define E1s 125000
#define E2s 32000
#define D_INs 128
#define D_Hs 256
#define D_OUTs 128

// ---------------------------------------------------------------------------
// Scatter-add: for each edge e, agg[dst[e]][:] += X[src[e]][:]; cnt[dst[e]] += 1
// One thread per float4 of one edge. logD4 = log2(D/4).
// ---------------------------------------------------------------------------
__launch_bounds__(256)
__global__ void scatter_add(const float* __restrict__ X,
                            const int* __restrict__ src,
                            const int* __restrict__ dst,
                            float* __restrict__ agg,
                            float* __restrict__ cnt,
                            int E, int D, int logD4)
{
    int gid = blockIdx.x * 256 + threadIdx.x;
    int e = gid >> logD4;
    if (e >= E) return;
    int c4 = gid & ((1 << logD4) - 1);     // which float4 within the row
    int c = c4 << 2;                       // float offset
    int s = src[e];
    int d = dst[e];
    float4 v = *(const float4*)&X[(size_t)s * D + c];
    float* out = &agg[(size_t)d * D + c];
    atomicAdd(out + 0, v.x);
    atomicAdd(out + 1, v.y);
    atomicAdd(out + 2, v.z);
    atomicAdd(out + 3, v.w);
    if (c4 == 0) atomicAdd(&cnt[d], 1.0f);
}

// ---------------------------------------------------------------------------
// mean: agg[i] /= max(cnt[row], 1)
// ---------------------------------------------------------------------------
__launch_bounds__(256)
__global__ void mean_div(float* __restrict__ agg,
                         const float* __restrict__ cnt,
                         int n, int logD)
{
    int gid = blockIdx.x * 256 + threadIdx.x;
    if (gid >= n) return;
    float c = cnt[gid >> logD];
    agg[gid] /= fmaxf(c, 1.0f);
}

// ---------------------------------------------------------------------------
// Fused dual GEMM: C[M,N] = maybe_relu( A1 @ W1^T + A2 @ W2^T + bias )
// A1,A2: M x K row-major;  W1,W2: N x K row-major;  bias: N
// 64x64 tile, BK=16, 256 threads, 4x4 accum per thread.
// ---------------------------------------------------------------------------
#define BM 64
#define BN 64
#define BK 16

__launch_bounds__(256)
__global__ void sage_gemm(const float* __restrict__ A1,
                          const float* __restrict__ A2,
                          const float* __restrict__ W1,
                          const float* __restrict__ W2,
                          const float* __restrict__ bias,
                          float* __restrict__ C,
                          int M, int N, int K, int relu)
{
    __shared__ float As1[BK][BM];
    __shared__ float As2[BK][BM];
    __shared__ float Ws1[BK][BN];
    __shared__ float Ws2[BK][BN];

    const int tid = threadIdx.x;
    const int tx = tid & 15;       // 0..15 (col group)
    const int ty = tid >> 4;       // 0..15 (row group)
    const int row0 = blockIdx.x * BM;
    const int col0 = blockIdx.y * BN;

    // loader mapping: 256 threads x float4 = 1024 elems = 64x16 tile
    const int lrow = tid >> 2;           // 0..63
    const int lk   = (tid & 3) << 2;     // 0,4,8,12

    float acc[4][4] = {};

    for (int k0 = 0; k0 < K; k0 += BK) {
        // A tiles (guard rows)
        {
            int gr = row0 + lrow;
            float4 a1 = {0.f, 0.f, 0.f, 0.f};
            float4 a2 = {0.f, 0.f, 0.f, 0.f};
            if (gr < M) {
                a1 = *(const float4*)&A1[(size_t)gr * K + k0 + lk];
                a2 = *(const float4*)&A2[(size_t)gr * K + k0 + lk];
            }
            As1[lk + 0][lrow] = a1.x; As1[lk + 1][lrow] = a1.y;
            As1[lk + 2][lrow] = a1.z; As1[lk + 3][lrow] = a1.w;
            As2[lk + 0][lrow] = a2.x; As2[lk + 1][lrow] = a2.y;
            As2[lk + 2][lrow] = a2.z; As2[lk + 3][lrow] = a2.w;
        }
        // W tiles (N multiple of 64 -> no guard)
        {
            int gc = col0 + lrow;
            float4 w1 = *(const float4*)&W1[(size_t)gc * K + k0 + lk];
            float4 w2 = *(const float4*)&W2[(size_t)gc * K + k0 + lk];
            Ws1[lk + 0][lrow] = w1.x; Ws1[lk + 1][lrow] = w1.y;
            Ws1[lk + 2][lrow] = w1.z; Ws1[lk + 3][lrow] = w1.w;
            Ws2[lk + 0][lrow] = w2.x; Ws2[lk + 1][lrow] = w2.y;
            Ws2[lk + 2][lrow] = w2.z; Ws2[lk + 3][lrow] = w2.w;
        }
        __syncthreads();

        #pragma unroll
        for (int kk = 0; kk < BK; ++kk) {
            float a1[4], a2[4], b1[4], b2[4];
            #pragma unroll
            for (int i = 0; i < 4; ++i) {
                a1[i] = As1[kk][ty * 4 + i];
                a2[i] = As2[kk][ty * 4 + i];
            }
            #pragma unroll
            for (int j = 0; j < 4; ++j) {
                b1[j] = Ws1[kk][tx * 4 + j];
                b2[j] = Ws2[kk][tx * 4 + j];
            }
            #pragma unroll
            for (int i = 0; i < 4; ++i)
                #pragma unroll
                for (int j = 0; j < 4; ++j)
                    acc[i][j] += a1[i] * b1[j] + a2[i] * b2[j];
        }
        __syncthreads();
    }

    const float4 bv = *(const float4*)&bias[col0 + tx * 4];
    #pragma unroll
    for (int i = 0; i < 4; ++i) {
        int r = row0 + ty * 4 + i;
        if (r < M) {
            float4 o;
            o.x = acc[i][0] + bv.x;
            o.y = acc[i][1] + bv.y;
            o.z = acc[i][2] + bv.z;
            o.w = acc[i][3] + bv.w;
            if (relu) {
                o.x = fmaxf(o.x, 0.f); o.y = fmaxf(o.y, 0.f);
                o.z = fmaxf(o.z, 0.f); o.w = fmaxf(o.w, 0.f);
            }
            *(float4*)&C[(size_t)r * N + col0 + tx * 4] = o;
        }
    }
}

// ---------------------------------------------------------------------------
// launch
// ---------------------------------------------------------------------------
extern "C" void kernel_launch(void* const* d_in, const int* in_sizes, int n_in,
                              void* d_out, int out_size, void* d_ws, size_t ws_size,
                              hipStream_t stream)
{
    const float* x   = (const float*)d_in[0];
    const int* src0  = (const int*)d_in[1];
    const int* dst0  = (const int*)d_in[2];
    const int* src1  = (const int*)d_in[3];
    const int* dst1  = (const int*)d_in[4];
    const int* src2  = (const int*)d_in[5];
    const int* dst2  = (const int*)d_in[6];
    const float* wl0 = (const float*)d_in[7];
    const float* wr0 = (const float*)d_in[8];
    const float* b0  = (const float*)d_in[9];
    const float* wl1 = (const float*)d_in[10];
    const float* wr1 = (const float*)d_in[11];
    const float* b1  = (const float*)d_in[12];
    const float* wl2 = (const float*)d_in[13];
    const float* wr2 = (const float*)d_in[14];
    const float* b2  = (const float*)d_in[15];

    float* ws = (float*)d_ws;
    // zero-init region (aggregates + counts), 64-float aligned offsets
    float* agg0 = ws;                                   // N1*128
    float* cnt0 = agg0 + (size_t)N1s * D_INs;           // 50000 (pad to 50048)
    float* agg1 = cnt0 + 50048;                         // N2*256
    float* cnt1 = agg1 + (size_t)N2s * D_Hs;            // 12500 (pad to 12544)
    float* agg2 = cnt1 + 12544;                         // N3*256
    float* cnt2 = agg2 + (size_t)N3s * D_Hs;            // 3200
    float* zend = cnt2 + 3200;
    // non-zeroed scratch
    float* h1 = zend;                                   // N1*256
    float* h2 = h1 + (size_t)N1s * D_Hs;                // N2*256

    size_t zero_bytes = (size_t)(zend - ws) * sizeof(float);
    hipMemsetAsync(d_ws, 0, zero_bytes, stream);

    // ---- layer 0: x (N0,128) -> h1 (N1,256), relu ----
    {
        int threads = E0s * (D_INs / 4);
        scatter_add<<<(threads + 255) / 256, 256, 0, stream>>>(
            x, src0, dst0, agg0, cnt0, E0s, D_INs, 5);
        int n = N1s * D_INs;
        mean_div<<<(n + 255) / 256, 256, 0, stream>>>(agg0, cnt0, n, 7);
        dim3 g((N1s + BM - 1) / BM, D_Hs / BN);
        sage_gemm<<<g, 256, 0, stream>>>(agg0, x, wl0, wr0, b0, h1,
                                         N1s, D_Hs, D_INs, 1);
    }
    // ---- layer 1: h1 (N1,256) -> h2 (N2,256), relu ----
    {
        int threads = E1s * (D_Hs / 4);
        scatter_add<<<(threads + 255) / 256, 256, 0, stream>>>(
            h1, src1, dst1, agg1, cnt1, E1s, D_Hs, 6);
        int n = N2s * D_Hs;
        mean_div<<<(n + 255) / 256, 256, 0, stream>>>(agg1, cnt1, n, 8);
        dim3 g((N2s + BM - 1) / BM, D_Hs / BN);
        sage_gemm<<<g, 256, 0, stream>>>(agg1, h1, wl1, wr1, b1, h2,
                                         N2s, D_Hs, D_Hs, 1);
    }
    // ---- layer 2: h2 (N2,256) -> out (N3,128), no relu ----
    {
        int threads = E2s * (D_Hs / 4);
        scatter_add<<<(threads + 255) / 256, 256, 0, stream>>>(
            h2, src2, dst2, agg2, cnt2, E2s, D_Hs, 6);
        int n = N3s * D_Hs;
        mean_div<<<(n + 255) / 256, 256, 0, stream>>>(agg2, cnt2, n, 8);
        dim3 g((N3s + BM - 1) / BM, D_OUTs / BN);
        sage_gemm<<<g, 256, 0, stream>>>(agg2, h2, wl2, wr2, b2, (float*)d_out,
                                         N3s, D_OUTs, D_Hs, 0);
    }
}

// Round 2
// 698.293 us; speedup vs baseline: 2.6463x; 2.6463x over previous
//
#include <hip/hip_runtime.h>

// Problem constants (from reference)
#define N0s 200000
#define N1s 50000
#define N2s 12500
#define N3s 3200
#define E0s 500000
#define E1s 125000
#define E2s 32000
#define D_INs 128
#define D_Hs 256
#define D_OUTs 128

// ---------------------------------------------------------------------------
// CSR build step 1: histogram of dst
// ---------------------------------------------------------------------------
__launch_bounds__(256)
__global__ void hist_kernel(const int* __restrict__ dst, int* __restrict__ cnt, int E)
{
    int e = blockIdx.x * 256 + threadIdx.x;
    if (e < E) atomicAdd(&cnt[dst[e]], 1);
}

// ---------------------------------------------------------------------------
// CSR build step 2: exclusive scan (single block, 1024 threads, chunked)
// off[0..n] written (off[n] = E); cursor is a second copy for the fill pass.
// ---------------------------------------------------------------------------
__launch_bounds__(1024)
__global__ void scan_off(const int* __restrict__ cnt,
                         int* __restrict__ off,
                         int* __restrict__ cursor, int n)
{
    __shared__ int sums[1024];
    const int t = threadIdx.x;
    const int chunk = (n + 1023) >> 10;
    const int lo = t * chunk;
    const int hi = min(lo + chunk, n);

    int s = 0;
    for (int i = lo; i < hi; ++i) s += cnt[i];
    sums[t] = s;
    __syncthreads();
    // Hillis-Steele inclusive scan over 1024 chunk sums
    for (int d = 1; d < 1024; d <<= 1) {
        int v = (t >= d) ? sums[t - d] : 0;
        __syncthreads();
        sums[t] += v;
        __syncthreads();
    }
    int run = (t == 0) ? 0 : sums[t - 1];
    for (int i = lo; i < hi; ++i) {
        off[i] = run; cursor[i] = run; run += cnt[i];
    }
    if (hi == n) off[n] = run;   // idempotent for tail threads (run == E)
}

// ---------------------------------------------------------------------------
// CSR build step 3: scatter edge srcs into buckets
// ---------------------------------------------------------------------------
__launch_bounds__(256)
__global__ void fill_eidx(const int* __restrict__ src, const int* __restrict__ dst,
                          int* __restrict__ cursor, int* __restrict__ eidx, int E)
{
    int e = blockIdx.x * 256 + threadIdx.x;
    if (e >= E) return;
    int p = atomicAdd(&cursor[dst[e]], 1);
    eidx[p] = src[e];
}

// ---------------------------------------------------------------------------
// Gather + mean: one (D/4)-lane group per destination row; float4 loads,
// coalesced writes, no fp atomics. logTpr = log2(D/4).
// ---------------------------------------------------------------------------
__launch_bounds__(256)
__global__ void gather_mean(const float* __restrict__ X,
                            const int* __restrict__ eidx,
                            const int* __restrict__ off,
                            float* __restrict__ out,
                            int n_tgt, int D, int logTpr)
{
    int gid = blockIdx.x * 256 + threadIdx.x;
    int row = gid >> logTpr;
    if (row >= n_tgt) return;
    int c = (gid & ((1 << logTpr) - 1)) << 2;   // float col offset

    int s = off[row];
    int e = off[row + 1];

    float4 acc = {0.f, 0.f, 0.f, 0.f};
    int i = s;
    for (; i + 2 <= e; i += 2) {
        int s0 = eidx[i], s1 = eidx[i + 1];
        float4 v0 = *(const float4*)&X[(size_t)s0 * D + c];
        float4 v1 = *(const float4*)&X[(size_t)s1 * D + c];
        acc.x += v0.x + v1.x; acc.y += v0.y + v1.y;
        acc.z += v0.z + v1.z; acc.w += v0.w + v1.w;
    }
    if (i < e) {
        float4 v0 = *(const float4*)&X[(size_t)eidx[i] * D + c];
        acc.x += v0.x; acc.y += v0.y; acc.z += v0.z; acc.w += v0.w;
    }
    float d = fmaxf((float)(e - s), 1.0f);
    float4 o;
    o.x = acc.x / d; o.y = acc.y / d; o.z = acc.z / d; o.w = acc.w / d;
    *(float4*)&out[(size_t)row * D + c] = o;
}

// ---------------------------------------------------------------------------
// Fused dual GEMM: C[M,N] = maybe_relu( A1 @ W1^T + A2 @ W2^T + bias )
// A1,A2: M x K row-major;  W1,W2: N x K row-major;  bias: N
// 64x64 tile, BK=16, 256 threads, 4x4 accum per thread.
// ---------------------------------------------------------------------------
#define BM 64
#define BN 64
#define BK 16

__launch_bounds__(256)
__global__ void sage_gemm(const float* __restrict__ A1,
                          const float* __restrict__ A2,
                          const float* __restrict__ W1,
                          const float* __restrict__ W2,
                          const float* __restrict__ bias,
                          float* __restrict__ C,
                          int M, int N, int K, int relu)
{
    __shared__ float As1[BK][BM];
    __shared__ float As2[BK][BM];
    __shared__ float Ws1[BK][BN];
    __shared__ float Ws2[BK][BN];

    const int tid = threadIdx.x;
    const int tx = tid & 15;       // 0..15 (col group)
    const int ty = tid >> 4;       // 0..15 (row group)
    const int row0 = blockIdx.x * BM;
    const int col0 = blockIdx.y * BN;

    const int lrow = tid >> 2;           // 0..63
    const int lk   = (tid & 3) << 2;     // 0,4,8,12

    float acc[4][4] = {};

    for (int k0 = 0; k0 < K; k0 += BK) {
        {
            int gr = row0 + lrow;
            float4 a1 = {0.f, 0.f, 0.f, 0.f};
            float4 a2 = {0.f, 0.f, 0.f, 0.f};
            if (gr < M) {
                a1 = *(const float4*)&A1[(size_t)gr * K + k0 + lk];
                a2 = *(const float4*)&A2[(size_t)gr * K + k0 + lk];
            }
            As1[lk + 0][lrow] = a1.x; As1[lk + 1][lrow] = a1.y;
            As1[lk + 2][lrow] = a1.z; As1[lk + 3][lrow] = a1.w;
            As2[lk + 0][lrow] = a2.x; As2[lk + 1][lrow] = a2.y;
            As2[lk + 2][lrow] = a2.z; As2[lk + 3][lrow] = a2.w;
        }
        {
            int gc = col0 + lrow;
            float4 w1 = *(const float4*)&W1[(size_t)gc * K + k0 + lk];
            float4 w2 = *(const float4*)&W2[(size_t)gc * K + k0 + lk];
            Ws1[lk + 0][lrow] = w1.x; Ws1[lk + 1][lrow] = w1.y;
            Ws1[lk + 2][lrow] = w1.z; Ws1[lk + 3][lrow] = w1.w;
            Ws2[lk + 0][lrow] = w2.x; Ws2[lk + 1][lrow] = w2.y;
            Ws2[lk + 2][lrow] = w2.z; Ws2[lk + 3][lrow] = w2.w;
        }
        __syncthreads();

        #pragma unroll
        for (int kk = 0; kk < BK; ++kk) {
            float a1[4], a2[4], b1[4], b2[4];
            #pragma unroll
            for (int i = 0; i < 4; ++i) {
                a1[i] = As1[kk][ty * 4 + i];
                a2[i] = As2[kk][ty * 4 + i];
            }
            #pragma unroll
            for (int j = 0; j < 4; ++j) {
                b1[j] = Ws1[kk][tx * 4 + j];
                b2[j] = Ws2[kk][tx * 4 + j];
            }
            #pragma unroll
            for (int i = 0; i < 4; ++i)
                #pragma unroll
                for (int j = 0; j < 4; ++j)
                    acc[i][j] += a1[i] * b1[j] + a2[i] * b2[j];
        }
        __syncthreads();
    }

    const float4 bv = *(const float4*)&bias[col0 + tx * 4];
    #pragma unroll
    for (int i = 0; i < 4; ++i) {
        int r = row0 + ty * 4 + i;
        if (r < M) {
            float4 o;
            o.x = acc[i][0] + bv.x;
            o.y = acc[i][1] + bv.y;
            o.z = acc[i][2] + bv.z;
            o.w = acc[i][3] + bv.w;
            if (relu) {
                o.x = fmaxf(o.x, 0.f); o.y = fmaxf(o.y, 0.f);
                o.z = fmaxf(o.z, 0.f); o.w = fmaxf(o.w, 0.f);
            }
            *(float4*)&C[(size_t)r * N + col0 + tx * 4] = o;
        }
    }
}

// ---------------------------------------------------------------------------
// launch
// ---------------------------------------------------------------------------
extern "C" void kernel_launch(void* const* d_in, const int* in_sizes, int n_in,
                              void* d_out, int out_size, void* d_ws, size_t ws_size,
                              hipStream_t stream)
{
    const float* x   = (const float*)d_in[0];
    const int* src0  = (const int*)d_in[1];
    const int* dst0  = (const int*)d_in[2];
    const int* src1  = (const int*)d_in[3];
    const int* dst1  = (const int*)d_in[4];
    const int* src2  = (const int*)d_in[5];
    const int* dst2  = (const int*)d_in[6];
    const float* wl0 = (const float*)d_in[7];
    const float* wr0 = (const float*)d_in[8];
    const float* b0  = (const float*)d_in[9];
    const float* wl1 = (const float*)d_in[10];
    const float* wr1 = (const float*)d_in[11];
    const float* b1  = (const float*)d_in[12];
    const float* wl2 = (const float*)d_in[13];
    const float* wr2 = (const float*)d_in[14];
    const float* b2  = (const float*)d_in[15];

    // Workspace layout (floats then ints). meanA region (6.4M floats) is
    // reused: mean0, then mean1, then mean2 (each dead before next use).
    float* ws = (float*)d_ws;
    float* meanA = ws;                                   // 6,400,000 floats
    float* h1 = meanA + (size_t)N1s * D_INs;             // 12,800,000 floats
    float* h2 = h1 + (size_t)N1s * D_Hs;                 // 3,200,000 floats
    int* ib = (int*)(h2 + (size_t)N2s * D_Hs);
    int* cnt    = ib;                                    // 50048
    int* off    = cnt + 50048;                           // 50056 (needs n+1)
    int* cursor = off + 50056;                           // 50048
    int* eidx   = cursor + 50048;                        // 500000

    // ---- layer 0: x (N0,128) --mean--> (N1,128) --gemm--> h1 (N1,256), relu
    {
        hipMemsetAsync(cnt, 0, 50048 * sizeof(int), stream);
        hist_kernel<<<(E0s + 255) / 256, 256, 0, stream>>>(dst0, cnt, E0s);
        scan_off<<<1, 1024, 0, stream>>>(cnt, off, cursor, N1s);
        fill_eidx<<<(E0s + 255) / 256, 256, 0, stream>>>(src0, dst0, cursor, eidx, E0s);
        int th = N1s * (D_INs / 4);
        gather_mean<<<(th + 255) / 256, 256, 0, stream>>>(x, eidx, off, meanA,
                                                          N1s, D_INs, 5);
        dim3 g((N1s + BM - 1) / BM, D_Hs / BN);
        sage_gemm<<<g, 256, 0, stream>>>(meanA, x, wl0, wr0, b0, h1,
                                         N1s, D_Hs, D_INs, 1);
    }
    // ---- layer 1: h1 (N1,256) --mean--> (N2,256) --gemm--> h2 (N2,256), relu
    {
        hipMemsetAsync(cnt, 0, 50048 * sizeof(int), stream);
        hist_kernel<<<(E1s + 255) / 256, 256, 0, stream>>>(dst1, cnt, E1s);
        scan_off<<<1, 1024, 0, stream>>>(cnt, off, cursor, N2s);
        fill_eidx<<<(E1s + 255) / 256, 256, 0, stream>>>(src1, dst1, cursor, eidx, E1s);
        int th = N2s * (D_Hs / 4);
        gather_mean<<<(th + 255) / 256, 256, 0, stream>>>(h1, eidx, off, meanA,
                                                          N2s, D_Hs, 6);
        dim3 g((N2s + BM - 1) / BM, D_Hs / BN);
        sage_gemm<<<g, 256, 0, stream>>>(meanA, h1, wl1, wr1, b1, h2,
                                         N2s, D_Hs, D_Hs, 1);
    }
    // ---- layer 2: h2 (N2,256) --mean--> (N3,256) --gemm--> out (N3,128)
    {
        hipMemsetAsync(cnt, 0, 50048 * sizeof(int), stream);
        hist_kernel<<<(E2s + 255) / 256, 256, 0, stream>>>(dst2, cnt, E2s);
        scan_off<<<1, 1024, 0, stream>>>(cnt, off, cursor, N3s);
        fill_eidx<<<(E2s + 255) / 256, 256, 0, stream>>>(src2, dst2, cursor, eidx, E2s);
        int th = N3s * (D_Hs / 4);
        gather_mean<<<(th + 255) / 256, 256, 0, stream>>>(h2, eidx, off, meanA,
                                                          N3s, D_Hs, 6);
        dim3 g((N3s + BM - 1) / BM, D_OUTs / BN);
        sage_gemm<<<g, 256, 0, stream>>>(meanA, h2, wl2, wr2, b2, (float*)d_out,
                                         N3s, D_OUTs, D_Hs, 0);
    }
}

// Round 3
// 540.536 us; speedup vs baseline: 3.4186x; 1.2919x over previous
//
#include <hip/hip_runtime.h>

// Problem constants (from reference)
#define N0s 200000
#define N1s 50000
#define N2s 12500
#define N3s 3200
#define E0s 500000
#define E1s 125000
#define E2s 32000
#define D_INs 128
#define D_Hs 256
#define D_OUTs 128

typedef __attribute__((ext_vector_type(8))) short short8;
typedef __attribute__((ext_vector_type(4))) float floatx4;

__device__ __forceinline__ unsigned short f32_to_bf16_rne(float f) {
    unsigned int u = __float_as_uint(f);
    u += 0x7fffu + ((u >> 16) & 1u);
    return (unsigned short)(u >> 16);
}
__device__ __forceinline__ float bf16_to_f32(unsigned short h) {
    return __uint_as_float(((unsigned int)h) << 16);
}

// ---------------------------------------------------------------------------
// fp32 -> bf16 cast (n multiple of 4)
// ---------------------------------------------------------------------------
__launch_bounds__(256)
__global__ void cast_bf16(const float* __restrict__ src,
                          unsigned short* __restrict__ dst, int n4)
{
    int gid = blockIdx.x * 256 + threadIdx.x;
    if (gid >= n4) return;
    float4 v = *(const float4*)&src[(size_t)gid * 4];
    ushort4 o;
    o.x = f32_to_bf16_rne(v.x);
    o.y = f32_to_bf16_rne(v.y);
    o.z = f32_to_bf16_rne(v.z);
    o.w = f32_to_bf16_rne(v.w);
    *(ushort4*)&dst[(size_t)gid * 4] = o;
}

// ---------------------------------------------------------------------------
// CSR build: histogram, scan, bucket-fill
// ---------------------------------------------------------------------------
__launch_bounds__(256)
__global__ void hist_kernel(const int* __restrict__ dst, int* __restrict__ cnt, int E)
{
    int e = blockIdx.x * 256 + threadIdx.x;
    if (e < E) atomicAdd(&cnt[dst[e]], 1);
}

__launch_bounds__(1024)
__global__ void scan_off(const int* __restrict__ cnt,
                         int* __restrict__ off,
                         int* __restrict__ cursor, int n)
{
    __shared__ int sums[1024];
    const int t = threadIdx.x;
    const int chunk = (n + 1023) >> 10;
    const int lo = t * chunk;
    const int hi = min(lo + chunk, n);

    int s = 0;
    for (int i = lo; i < hi; ++i) s += cnt[i];
    sums[t] = s;
    __syncthreads();
    for (int d = 1; d < 1024; d <<= 1) {
        int v = (t >= d) ? sums[t - d] : 0;
        __syncthreads();
        sums[t] += v;
        __syncthreads();
    }
    int run = (t == 0) ? 0 : sums[t - 1];
    for (int i = lo; i < hi; ++i) {
        off[i] = run; cursor[i] = run; run += cnt[i];
    }
    if (hi == n) off[n] = run;
}

__launch_bounds__(256)
__global__ void fill_eidx(const int* __restrict__ src, const int* __restrict__ dst,
                          int* __restrict__ cursor, int* __restrict__ eidx, int E)
{
    int e = blockIdx.x * 256 + threadIdx.x;
    if (e >= E) return;
    int p = atomicAdd(&cursor[dst[e]], 1);
    eidx[p] = src[e];
}

// ---------------------------------------------------------------------------
// Gather + mean over bf16 rows, fp32 accumulate, bf16 output.
// (D/4) threads per row, 4 bf16 (8B) per thread. logTpr = log2(D/4).
// ---------------------------------------------------------------------------
__launch_bounds__(256)
__global__ void gather_mean(const unsigned short* __restrict__ X,
                            const int* __restrict__ eidx,
                            const int* __restrict__ off,
                            unsigned short* __restrict__ out,
                            int n_tgt, int D, int logTpr)
{
    int gid = blockIdx.x * 256 + threadIdx.x;
    int row = gid >> logTpr;
    if (row >= n_tgt) return;
    int c = (gid & ((1 << logTpr) - 1)) << 2;

    int s = off[row];
    int e = off[row + 1];

    float a0 = 0.f, a1 = 0.f, a2 = 0.f, a3 = 0.f;
    int i = s;
    for (; i + 2 <= e; i += 2) {
        int s0 = eidx[i], s1 = eidx[i + 1];
        ushort4 v0 = *(const ushort4*)&X[(size_t)s0 * D + c];
        ushort4 v1 = *(const ushort4*)&X[(size_t)s1 * D + c];
        a0 += bf16_to_f32(v0.x) + bf16_to_f32(v1.x);
        a1 += bf16_to_f32(v0.y) + bf16_to_f32(v1.y);
        a2 += bf16_to_f32(v0.z) + bf16_to_f32(v1.z);
        a3 += bf16_to_f32(v0.w) + bf16_to_f32(v1.w);
    }
    if (i < e) {
        ushort4 v0 = *(const ushort4*)&X[(size_t)eidx[i] * D + c];
        a0 += bf16_to_f32(v0.x); a1 += bf16_to_f32(v0.y);
        a2 += bf16_to_f32(v0.z); a3 += bf16_to_f32(v0.w);
    }
    float d = fmaxf((float)(e - s), 1.0f);
    float inv = 1.0f / d;
    ushort4 o;
    o.x = f32_to_bf16_rne(a0 * inv);
    o.y = f32_to_bf16_rne(a1 * inv);
    o.z = f32_to_bf16_rne(a2 * inv);
    o.w = f32_to_bf16_rne(a3 * inv);
    *(ushort4*)&out[(size_t)row * D + c] = o;
}

// ---------------------------------------------------------------------------
// bf16 MFMA dual-GEMM: C[M,N] = maybe_relu(A1@W1^T + A2@W2^T + bias)
// A1,A2: M x K row-major bf16; W1,W2: N x K row-major bf16; bias fp32.
// 128x128 tile, 4 waves (2x2 of 64x64), v_mfma_f32_16x16x32_bf16, BK=32.
// LDS row stride 40 shorts (80B): conflict-free b128 fragment reads.
// Output fp32 or bf16 (out_bf16).
// ---------------------------------------------------------------------------
__launch_bounds__(256)
__global__ void mfma_gemm(const unsigned short* __restrict__ A1,
                          const unsigned short* __restrict__ A2,
                          const unsigned short* __restrict__ W1,
                          const unsigned short* __restrict__ W2,
                          const float* __restrict__ bias,
                          void* __restrict__ Cout,
                          int M, int N, int K1, int K2,
                          int relu, int out_bf16)
{
    __shared__ unsigned short As[128][40];
    __shared__ unsigned short Bs[128][40];

    const int tid  = threadIdx.x;
    const int wave = tid >> 6;
    const int lane = tid & 63;
    const int quad = lane >> 4;
    const int lr   = lane & 15;
    const int wm   = wave >> 1;      // 0..1
    const int wn   = wave & 1;       // 0..1
    const int row0 = blockIdx.x * 128;
    const int col0 = blockIdx.y * 128;

    floatx4 acc[4][4] = {};

    const unsigned short* Aseg[2] = {A1, A2};
    const unsigned short* Wseg[2] = {W1, W2};
    const int Ks[2] = {K1, K2};

    for (int seg = 0; seg < 2; ++seg) {
        const unsigned short* Ap = Aseg[seg];
        const unsigned short* Wp = Wseg[seg];
        const int K = Ks[seg];

        for (int k0 = 0; k0 < K; k0 += 32) {
            // stage A-tile: 128 rows x 32 k = 512 x (8 shorts); 2 per thread
            #pragma unroll
            for (int it = 0; it < 2; ++it) {
                int sid = tid + it * 256;
                int r = sid >> 2;
                int sc = (sid & 3) << 3;
                int gr = min(row0 + r, M - 1);
                uint4 v = *(const uint4*)&Ap[(size_t)gr * K + k0 + sc];
                *(uint4*)&As[r][sc] = v;
            }
            // stage B-tile: 128 W-rows x 32 k (N multiple of 128 -> no guard)
            #pragma unroll
            for (int it = 0; it < 2; ++it) {
                int sid = tid + it * 256;
                int r = sid >> 2;
                int sc = (sid & 3) << 3;
                uint4 v = *(const uint4*)&Wp[(size_t)(col0 + r) * K + k0 + sc];
                *(uint4*)&Bs[r][sc] = v;
            }
            __syncthreads();

            short8 afr[4], bfr[4];
            #pragma unroll
            for (int mt = 0; mt < 4; ++mt)
                afr[mt] = *(const short8*)&As[wm * 64 + mt * 16 + lr][quad * 8];
            #pragma unroll
            for (int nt = 0; nt < 4; ++nt)
                bfr[nt] = *(const short8*)&Bs[wn * 64 + nt * 16 + lr][quad * 8];

            #pragma unroll
            for (int mt = 0; mt < 4; ++mt)
                #pragma unroll
                for (int nt = 0; nt < 4; ++nt)
                    acc[mt][nt] = __builtin_amdgcn_mfma_f32_16x16x32_bf16(
                        afr[mt], bfr[nt], acc[mt][nt], 0, 0, 0);

            __syncthreads();
        }
    }

    // epilogue: row = quad*4 + reg, col = lr  (m89-verified C/D layout)
    #pragma unroll
    for (int nt = 0; nt < 4; ++nt) {
        int gc = col0 + wn * 64 + nt * 16 + lr;
        float bv = bias[gc];
        #pragma unroll
        for (int mt = 0; mt < 4; ++mt) {
            #pragma unroll
            for (int reg = 0; reg < 4; ++reg) {
                int gr = row0 + wm * 64 + mt * 16 + quad * 4 + reg;
                if (gr < M) {
                    float v = acc[mt][nt][reg] + bv;
                    if (relu) v = fmaxf(v, 0.f);
                    if (out_bf16)
                        ((unsigned short*)Cout)[(size_t)gr * N + gc] = f32_to_bf16_rne(v);
                    else
                        ((float*)Cout)[(size_t)gr * N + gc] = v;
                }
            }
        }
    }
}

// ---------------------------------------------------------------------------
// launch
// ---------------------------------------------------------------------------
extern "C" void kernel_launch(void* const* d_in, const int* in_sizes, int n_in,
                              void* d_out, int out_size, void* d_ws, size_t ws_size,
                              hipStream_t stream)
{
    const float* x   = (const float*)d_in[0];
    const int* src0  = (const int*)d_in[1];
    const int* dst0  = (const int*)d_in[2];
    const int* src1  = (const int*)d_in[3];
    const int* dst1  = (const int*)d_in[4];
    const int* src2  = (const int*)d_in[5];
    const int* dst2  = (const int*)d_in[6];
    const float* wl0 = (const float*)d_in[7];
    const float* wr0 = (const float*)d_in[8];
    const float* b0  = (const float*)d_in[9];
    const float* wl1 = (const float*)d_in[10];
    const float* wr1 = (const float*)d_in[11];
    const float* b1  = (const float*)d_in[12];
    const float* wl2 = (const float*)d_in[13];
    const float* wr2 = (const float*)d_in[14];
    const float* b2  = (const float*)d_in[15];

    // Workspace layout (all bf16 arrays sized in multiples of 64 shorts)
    unsigned short* ws = (unsigned short*)d_ws;
    unsigned short* xb    = ws;                                 // 25,600,000
    unsigned short* h1    = xb + (size_t)N0s * D_INs;           // 12,800,000
    unsigned short* h2    = h1 + (size_t)N1s * D_Hs;            //  3,200,000
    unsigned short* meanA = h2 + (size_t)N2s * D_Hs;            //  6,400,000
    unsigned short* wb    = meanA + (size_t)N1s * D_INs;
    unsigned short* wl0b = wb;               // 32768
    unsigned short* wr0b = wl0b + 32768;
    unsigned short* wl1b = wr0b + 32768;     // 65536
    unsigned short* wr1b = wl1b + 65536;
    unsigned short* wl2b = wr1b + 65536;     // 32768
    unsigned short* wr2b = wl2b + 32768;
    int* ib = (int*)(wr2b + 32768);
    int* cnt    = ib;                        // 50048
    int* off    = cnt + 50048;               // 50056
    int* cursor = off + 50056;               // 50048
    int* eidx   = cursor + 50048;            // 500000

    // casts
    cast_bf16<<<(N0s * D_INs / 4 + 255) / 256, 256, 0, stream>>>(x, xb, N0s * D_INs / 4);
    cast_bf16<<<(32768 / 4 + 255) / 256, 256, 0, stream>>>(wl0, wl0b, 32768 / 4);
    cast_bf16<<<(32768 / 4 + 255) / 256, 256, 0, stream>>>(wr0, wr0b, 32768 / 4);
    cast_bf16<<<(65536 / 4 + 255) / 256, 256, 0, stream>>>(wl1, wl1b, 65536 / 4);
    cast_bf16<<<(65536 / 4 + 255) / 256, 256, 0, stream>>>(wr1, wr1b, 65536 / 4);
    cast_bf16<<<(32768 / 4 + 255) / 256, 256, 0, stream>>>(wl2, wl2b, 32768 / 4);
    cast_bf16<<<(32768 / 4 + 255) / 256, 256, 0, stream>>>(wr2, wr2b, 32768 / 4);

    // ---- layer 0: x (N0,128) -> h1 (N1,256) bf16, relu ----
    {
        hipMemsetAsync(cnt, 0, 50048 * sizeof(int), stream);
        hist_kernel<<<(E0s + 255) / 256, 256, 0, stream>>>(dst0, cnt, E0s);
        scan_off<<<1, 1024, 0, stream>>>(cnt, off, cursor, N1s);
        fill_eidx<<<(E0s + 255) / 256, 256, 0, stream>>>(src0, dst0, cursor, eidx, E0s);
        int th = N1s * (D_INs / 4);
        gather_mean<<<(th + 255) / 256, 256, 0, stream>>>(xb, eidx, off, meanA,
                                                          N1s, D_INs, 5);
        dim3 g((N1s + 127) / 128, D_Hs / 128);
        mfma_gemm<<<g, 256, 0, stream>>>(meanA, xb, wl0b, wr0b, b0, h1,
                                         N1s, D_Hs, D_INs, D_INs, 1, 1);
    }
    // ---- layer 1: h1 (N1,256) -> h2 (N2,256) bf16, relu ----
    {
        hipMemsetAsync(cnt, 0, 50048 * sizeof(int), stream);
        hist_kernel<<<(E1s + 255) / 256, 256, 0, stream>>>(dst1, cnt, E1s);
        scan_off<<<1, 1024, 0, stream>>>(cnt, off, cursor, N2s);
        fill_eidx<<<(E1s + 255) / 256, 256, 0, stream>>>(src1, dst1, cursor, eidx, E1s);
        int th = N2s * (D_Hs / 4);
        gather_mean<<<(th + 255) / 256, 256, 0, stream>>>(h1, eidx, off, meanA,
                                                          N2s, D_Hs, 6);
        dim3 g((N2s + 127) / 128, D_Hs / 128);
        mfma_gemm<<<g, 256, 0, stream>>>(meanA, h1, wl1b, wr1b, b1, h2,
                                         N2s, D_Hs, D_Hs, D_Hs, 1, 1);
    }
    // ---- layer 2: h2 (N2,256) -> out (N3,128) fp32 ----
    {
        hipMemsetAsync(cnt, 0, 50048 * sizeof(int), stream);
        hist_kernel<<<(E2s + 255) / 256, 256, 0, stream>>>(dst2, cnt, E2s);
        scan_off<<<1, 1024, 0, stream>>>(cnt, off, cursor, N3s);
        fill_eidx<<<(E2s + 255) / 256, 256, 0, stream>>>(src2, dst2, cursor, eidx, E2s);
        int th = N3s * (D_Hs / 4);
        gather_mean<<<(th + 255) / 256, 256, 0, stream>>>(h2, eidx, off, meanA,
                                                          N3s, D_Hs, 6);
        dim3 g((N3s + 127) / 128, D_OUTs / 128);
        mfma_gemm<<<g, 256, 0, stream>>>(meanA, h2, wl2b, wr2b, b2, (float*)d_out,
                                         N3s, D_OUTs, D_Hs, D_Hs, 0, 0);
    }
}

// Round 4
// 424.061 us; speedup vs baseline: 4.3575x; 1.2747x over previous
//
#include <hip/hip_runtime.h>

// Problem constants (from reference)
#define N0s 200000
#define N1s 50000
#define N2s 12500
#define N3s 3200
#define E0s 500000
#define E1s 125000
#define E2s 32000
#define D_INs 128
#define D_Hs 256
#define D_OUTs 128

typedef __attribute__((ext_vector_type(8))) short short8;
typedef __attribute__((ext_vector_type(4))) float floatx4;

__device__ __forceinline__ unsigned short f32_to_bf16_rne(float f) {
    unsigned int u = __float_as_uint(f);
    u += 0x7fffu + ((u >> 16) & 1u);
    return (unsigned short)(u >> 16);
}
__device__ __forceinline__ float bf16_to_f32(unsigned short h) {
    return __uint_as_float(((unsigned int)h) << 16);
}

// ---------------------------------------------------------------------------
// fp32 -> bf16 cast (n4 = count of float4 groups)
// ---------------------------------------------------------------------------
__launch_bounds__(256)
__global__ void cast_bf16(const float* __restrict__ src,
                          unsigned short* __restrict__ dst, int n4)
{
    int gid = blockIdx.x * 256 + threadIdx.x;
    if (gid >= n4) return;
    float4 v = *(const float4*)&src[(size_t)gid * 4];
    ushort4 o;
    o.x = f32_to_bf16_rne(v.x);
    o.y = f32_to_bf16_rne(v.y);
    o.z = f32_to_bf16_rne(v.z);
    o.w = f32_to_bf16_rne(v.w);
    *(ushort4*)&dst[(size_t)gid * 4] = o;
}

// All 6 weight matrices in one launch. Sizes in float4 units.
struct WCast { const float* s[6]; unsigned short* d[6]; };
__launch_bounds__(256)
__global__ void cast_weights(WCast wc)
{
    int gid = blockIdx.x * 256 + threadIdx.x;   // 0 .. 65535
    int seg, base;
    if      (gid < 8192)  { seg = 0; base = 0; }
    else if (gid < 16384) { seg = 1; base = 8192; }
    else if (gid < 32768) { seg = 2; base = 16384; }
    else if (gid < 49152) { seg = 3; base = 32768; }
    else if (gid < 57344) { seg = 4; base = 49152; }
    else                  { seg = 5; base = 57344; }
    int i = gid - base;
    float4 v = *(const float4*)&wc.s[seg][(size_t)i * 4];
    ushort4 o;
    o.x = f32_to_bf16_rne(v.x);
    o.y = f32_to_bf16_rne(v.y);
    o.z = f32_to_bf16_rne(v.z);
    o.w = f32_to_bf16_rne(v.w);
    *(ushort4*)&wc.d[seg][(size_t)i * 4] = o;
}

// ---------------------------------------------------------------------------
// CSR build, all three layers fused.
// ---------------------------------------------------------------------------
struct Csr3 {
    const int *src0, *dst0, *src1, *dst1, *src2, *dst2;
    int *cnt0, *cnt1, *cnt2;
    int *off0, *off1, *off2;
    int *cur0, *cur1, *cur2;
    int *eidx0, *eidx1, *eidx2;
};

__launch_bounds__(256)
__global__ void hist3(Csr3 c)
{
    int e = blockIdx.x * 256 + threadIdx.x;
    if (e < E0s) {
        atomicAdd(&c.cnt0[c.dst0[e]], 1);
    } else if (e < E0s + E1s) {
        atomicAdd(&c.cnt1[c.dst1[e - E0s]], 1);
    } else if (e < E0s + E1s + E2s) {
        atomicAdd(&c.cnt2[c.dst2[e - E0s - E1s]], 1);
    }
}

__launch_bounds__(256)
__global__ void fill3(Csr3 c)
{
    int e = blockIdx.x * 256 + threadIdx.x;
    if (e < E0s) {
        int p = atomicAdd(&c.cur0[c.dst0[e]], 1);
        c.eidx0[p] = c.src0[e];
    } else if (e < E0s + E1s) {
        int i = e - E0s;
        int p = atomicAdd(&c.cur1[c.dst1[i]], 1);
        c.eidx1[p] = c.src1[i];
    } else if (e < E0s + E1s + E2s) {
        int i = e - E0s - E1s;
        int p = atomicAdd(&c.cur2[c.dst2[i]], 1);
        c.eidx2[p] = c.src2[i];
    }
}

// One block per layer; tile-wise scan: coalesced load, wave shfl scan,
// 16-wave LDS combine, coalesced store.
__launch_bounds__(1024)
__global__ void scan3(Csr3 c)
{
    const int* cnt; int* off; int* cur; int n;
    if (blockIdx.x == 0)      { cnt = c.cnt0; off = c.off0; cur = c.cur0; n = N1s; }
    else if (blockIdx.x == 1) { cnt = c.cnt1; off = c.off1; cur = c.cur1; n = N2s; }
    else                      { cnt = c.cnt2; off = c.off2; cur = c.cur2; n = N3s; }

    __shared__ int wsum[16];
    const int t = threadIdx.x;
    const int lane = t & 63;
    const int wave = t >> 6;

    int run = 0;
    for (int base = 0; base < n; base += 1024) {
        int i = base + t;
        int v = (i < n) ? cnt[i] : 0;
        // wave inclusive scan
        int x = v;
        #pragma unroll
        for (int d = 1; d < 64; d <<= 1) {
            int y = __shfl_up(x, d, 64);
            if (lane >= d) x += y;
        }
        if (lane == 63) wsum[wave] = x;
        __syncthreads();
        if (wave == 0 && lane < 16) {
            int xs = wsum[lane];
            #pragma unroll
            for (int d = 1; d < 16; d <<= 1) {
                int y = __shfl_up(xs, d, 64);
                if (lane >= d) xs += y;
            }
            wsum[lane] = xs;   // inclusive over wave sums
        }
        __syncthreads();
        int wbase = (wave == 0) ? 0 : wsum[wave - 1];
        int excl = run + wbase + x - v;
        if (i < n) { off[i] = excl; cur[i] = excl; }
        run += wsum[15];
        __syncthreads();   // wsum reused next tile
    }
    if (t == 0) off[n] = run;
}

// ---------------------------------------------------------------------------
// Gather + mean over bf16 rows, fp32 accumulate, bf16 output.
// (D/4) threads per row, 4 bf16 (8B) per thread. logTpr = log2(D/4).
// ---------------------------------------------------------------------------
__launch_bounds__(256)
__global__ void gather_mean(const unsigned short* __restrict__ X,
                            const int* __restrict__ eidx,
                            const int* __restrict__ off,
                            unsigned short* __restrict__ out,
                            int n_tgt, int D, int logTpr)
{
    int gid = blockIdx.x * 256 + threadIdx.x;
    int row = gid >> logTpr;
    if (row >= n_tgt) return;
    int c = (gid & ((1 << logTpr) - 1)) << 2;

    int s = off[row];
    int e = off[row + 1];

    float a0 = 0.f, a1 = 0.f, a2 = 0.f, a3 = 0.f;
    int i = s;
    for (; i + 2 <= e; i += 2) {
        int s0 = eidx[i], s1 = eidx[i + 1];
        ushort4 v0 = *(const ushort4*)&X[(size_t)s0 * D + c];
        ushort4 v1 = *(const ushort4*)&X[(size_t)s1 * D + c];
        a0 += bf16_to_f32(v0.x) + bf16_to_f32(v1.x);
        a1 += bf16_to_f32(v0.y) + bf16_to_f32(v1.y);
        a2 += bf16_to_f32(v0.z) + bf16_to_f32(v1.z);
        a3 += bf16_to_f32(v0.w) + bf16_to_f32(v1.w);
    }
    if (i < e) {
        ushort4 v0 = *(const ushort4*)&X[(size_t)eidx[i] * D + c];
        a0 += bf16_to_f32(v0.x); a1 += bf16_to_f32(v0.y);
        a2 += bf16_to_f32(v0.z); a3 += bf16_to_f32(v0.w);
    }
    float d = fmaxf((float)(e - s), 1.0f);
    float inv = 1.0f / d;
    ushort4 o;
    o.x = f32_to_bf16_rne(a0 * inv);
    o.y = f32_to_bf16_rne(a1 * inv);
    o.z = f32_to_bf16_rne(a2 * inv);
    o.w = f32_to_bf16_rne(a3 * inv);
    *(ushort4*)&out[(size_t)row * D + c] = o;
}

// ---------------------------------------------------------------------------
// bf16 MFMA dual-GEMM: C[M,N] = maybe_relu(A1@W1^T + A2@W2^T + bias)
// 128x128 tile, 4 waves (2x2 of 64x64), v_mfma_f32_16x16x32_bf16, BK=32.
// LDS row stride 40 shorts: conflict-free b128 fragment reads.
// ---------------------------------------------------------------------------
__launch_bounds__(256)
__global__ void mfma_gemm(const unsigned short* __restrict__ A1,
                          const unsigned short* __restrict__ A2,
                          const unsigned short* __restrict__ W1,
                          const unsigned short* __restrict__ W2,
                          const float* __restrict__ bias,
                          void* __restrict__ Cout,
                          int M, int N, int K1, int K2,
                          int relu, int out_bf16)
{
    __shared__ unsigned short As[128][40];
    __shared__ unsigned short Bs[128][40];

    const int tid  = threadIdx.x;
    const int wave = tid >> 6;
    const int lane = tid & 63;
    const int quad = lane >> 4;
    const int lr   = lane & 15;
    const int wm   = wave >> 1;
    const int wn   = wave & 1;
    const int row0 = blockIdx.x * 128;
    const int col0 = blockIdx.y * 128;

    floatx4 acc[4][4] = {};

    const unsigned short* Aseg[2] = {A1, A2};
    const unsigned short* Wseg[2] = {W1, W2};
    const int Ks[2] = {K1, K2};

    for (int seg = 0; seg < 2; ++seg) {
        const unsigned short* Ap = Aseg[seg];
        const unsigned short* Wp = Wseg[seg];
        const int K = Ks[seg];

        for (int k0 = 0; k0 < K; k0 += 32) {
            #pragma unroll
            for (int it = 0; it < 2; ++it) {
                int sid = tid + it * 256;
                int r = sid >> 2;
                int sc = (sid & 3) << 3;
                int gr = min(row0 + r, M - 1);
                uint4 v = *(const uint4*)&Ap[(size_t)gr * K + k0 + sc];
                *(uint4*)&As[r][sc] = v;
            }
            #pragma unroll
            for (int it = 0; it < 2; ++it) {
                int sid = tid + it * 256;
                int r = sid >> 2;
                int sc = (sid & 3) << 3;
                uint4 v = *(const uint4*)&Wp[(size_t)(col0 + r) * K + k0 + sc];
                *(uint4*)&Bs[r][sc] = v;
            }
            __syncthreads();

            short8 afr[4], bfr[4];
            #pragma unroll
            for (int mt = 0; mt < 4; ++mt)
                afr[mt] = *(const short8*)&As[wm * 64 + mt * 16 + lr][quad * 8];
            #pragma unroll
            for (int nt = 0; nt < 4; ++nt)
                bfr[nt] = *(const short8*)&Bs[wn * 64 + nt * 16 + lr][quad * 8];

            #pragma unroll
            for (int mt = 0; mt < 4; ++mt)
                #pragma unroll
                for (int nt = 0; nt < 4; ++nt)
                    acc[mt][nt] = __builtin_amdgcn_mfma_f32_16x16x32_bf16(
                        afr[mt], bfr[nt], acc[mt][nt], 0, 0, 0);

            __syncthreads();
        }
    }

    #pragma unroll
    for (int nt = 0; nt < 4; ++nt) {
        int gc = col0 + wn * 64 + nt * 16 + lr;
        float bv = bias[gc];
        #pragma unroll
        for (int mt = 0; mt < 4; ++mt) {
            #pragma unroll
            for (int reg = 0; reg < 4; ++reg) {
                int gr = row0 + wm * 64 + mt * 16 + quad * 4 + reg;
                if (gr < M) {
                    float v = acc[mt][nt][reg] + bv;
                    if (relu) v = fmaxf(v, 0.f);
                    if (out_bf16)
                        ((unsigned short*)Cout)[(size_t)gr * N + gc] = f32_to_bf16_rne(v);
                    else
                        ((float*)Cout)[(size_t)gr * N + gc] = v;
                }
            }
        }
    }
}

// ---------------------------------------------------------------------------
// launch
// ---------------------------------------------------------------------------
extern "C" void kernel_launch(void* const* d_in, const int* in_sizes, int n_in,
                              void* d_out, int out_size, void* d_ws, size_t ws_size,
                              hipStream_t stream)
{
    const float* x   = (const float*)d_in[0];
    const int* src0  = (const int*)d_in[1];
    const int* dst0  = (const int*)d_in[2];
    const int* src1  = (const int*)d_in[3];
    const int* dst1  = (const int*)d_in[4];
    const int* src2  = (const int*)d_in[5];
    const int* dst2  = (const int*)d_in[6];
    const float* wl0 = (const float*)d_in[7];
    const float* wr0 = (const float*)d_in[8];
    const float* b0  = (const float*)d_in[9];
    const float* wl1 = (const float*)d_in[10];
    const float* wr1 = (const float*)d_in[11];
    const float* b1  = (const float*)d_in[12];
    const float* wl2 = (const float*)d_in[13];
    const float* wr2 = (const float*)d_in[14];
    const float* b2  = (const float*)d_in[15];

    // Workspace layout
    unsigned short* ws = (unsigned short*)d_ws;
    unsigned short* xb    = ws;                                 // 25,600,000
    unsigned short* h1    = xb + (size_t)N0s * D_INs;           // 12,800,000
    unsigned short* h2    = h1 + (size_t)N1s * D_Hs;            //  3,200,000
    unsigned short* meanA = h2 + (size_t)N2s * D_Hs;            //  6,400,000
    unsigned short* wb    = meanA + (size_t)N1s * D_INs;
    unsigned short* wl0b = wb;               // 32768
    unsigned short* wr0b = wl0b + 32768;
    unsigned short* wl1b = wr0b + 32768;     // 65536
    unsigned short* wr1b = wl1b + 65536;
    unsigned short* wl2b = wr1b + 65536;     // 32768
    unsigned short* wr2b = wl2b + 32768;
    int* ib = (int*)(wr2b + 32768);
    // cnt arrays contiguous -> one memset
    int* cnt0 = ib;                          // 50048
    int* cnt1 = cnt0 + 50048;                // 12544
    int* cnt2 = cnt1 + 12544;                // 3264
    int* off0 = cnt2 + 3264;                 // 50056
    int* off1 = off0 + 50056;                // 12544
    int* off2 = off1 + 12544;                // 3264
    int* cur0 = off2 + 3264;                 // 50048
    int* cur1 = cur0 + 50048;                // 12544
    int* cur2 = cur1 + 12544;                // 3264
    int* eidx0 = cur2 + 3264;                // 500000
    int* eidx1 = eidx0 + 500000;             // 125000
    int* eidx2 = eidx1 + 125000;             // 32000

    Csr3 c;
    c.src0 = src0; c.dst0 = dst0; c.src1 = src1; c.dst1 = dst1;
    c.src2 = src2; c.dst2 = dst2;
    c.cnt0 = cnt0; c.cnt1 = cnt1; c.cnt2 = cnt2;
    c.off0 = off0; c.off1 = off1; c.off2 = off2;
    c.cur0 = cur0; c.cur1 = cur1; c.cur2 = cur2;
    c.eidx0 = eidx0; c.eidx1 = eidx1; c.eidx2 = eidx2;

    // --- CSR build for all 3 layers (feature-independent) ---
    hipMemsetAsync(cnt0, 0, (50048 + 12544 + 3264) * sizeof(int), stream);
    const int Etot = E0s + E1s + E2s;
    hist3<<<(Etot + 255) / 256, 256, 0, stream>>>(c);
    scan3<<<3, 1024, 0, stream>>>(c);
    fill3<<<(Etot + 255) / 256, 256, 0, stream>>>(c);

    // --- casts ---
    cast_bf16<<<(N0s * D_INs / 4 + 255) / 256, 256, 0, stream>>>(x, xb, N0s * D_INs / 4);
    WCast wc;
    wc.s[0] = wl0; wc.s[1] = wr0; wc.s[2] = wl1;
    wc.s[3] = wr1; wc.s[4] = wl2; wc.s[5] = wr2;
    wc.d[0] = wl0b; wc.d[1] = wr0b; wc.d[2] = wl1b;
    wc.d[3] = wr1b; wc.d[4] = wl2b; wc.d[5] = wr2b;
    cast_weights<<<65536 / 256, 256, 0, stream>>>(wc);

    // ---- layer 0: x (N0,128) -> h1 (N1,256) bf16, relu ----
    {
        int th = N1s * (D_INs / 4);
        gather_mean<<<(th + 255) / 256, 256, 0, stream>>>(xb, eidx0, off0, meanA,
                                                          N1s, D_INs, 5);
        dim3 g((N1s + 127) / 128, D_Hs / 128);
        mfma_gemm<<<g, 256, 0, stream>>>(meanA, xb, wl0b, wr0b, b0, h1,
                                         N1s, D_Hs, D_INs, D_INs, 1, 1);
    }
    // ---- layer 1: h1 (N1,256) -> h2 (N2,256) bf16, relu ----
    {
        int th = N2s * (D_Hs / 4);
        gather_mean<<<(th + 255) / 256, 256, 0, stream>>>(h1, eidx1, off1, meanA,
                                                          N2s, D_Hs, 6);
        dim3 g((N2s + 127) / 128, D_Hs / 128);
        mfma_gemm<<<g, 256, 0, stream>>>(meanA, h1, wl1b, wr1b, b1, h2,
                                         N2s, D_Hs, D_Hs, D_Hs, 1, 1);
    }
    // ---- layer 2: h2 (N2,256) -> out (N3,128) fp32 ----
    {
        int th = N3s * (D_Hs / 4);
        gather_mean<<<(th + 255) / 256, 256, 0, stream>>>(h2, eidx2, off2, meanA,
                                                          N3s, D_Hs, 6);
        dim3 g((N3s + 127) / 128, D_OUTs / 128);
        mfma_gemm<<<g, 256, 0, stream>>>(meanA, h2, wl2b, wr2b, b2, (float*)d_out,
                                         N3s, D_OUTs, D_Hs, D_Hs, 0, 0);
    }
}

// Round 5
// 410.318 us; speedup vs baseline: 4.5035x; 1.0335x over previous
//
#include <hip/hip_runtime.h>

// Problem constants (from reference)
#define N0s 200000
#define N1s 50000
#define N2s 12500
#define N3s 3200
#define E0s 500000
#define E1s 125000
#define E2s 32000
#define D_INs 128
#define D_Hs 256
#define D_OUTs 128

// scan tiling: 2048 elements per tile
#define TILE 2048
#define T0 25            // ceil(50000/2048)
#define T1 7             // ceil(12500/2048)
#define T2 2             // ceil(3200/2048)
#define TILES (T0 + T1 + T2)   // 34

typedef __attribute__((ext_vector_type(8))) short short8;
typedef __attribute__((ext_vector_type(4))) float floatx4;

__device__ __forceinline__ unsigned short f32_to_bf16_rne(float f) {
    unsigned int u = __float_as_uint(f);
    u += 0x7fffu + ((u >> 16) & 1u);
    return (unsigned short)(u >> 16);
}
__device__ __forceinline__ float bf16_to_f32(unsigned short h) {
    return __uint_as_float(((unsigned int)h) << 16);
}

// ---------------------------------------------------------------------------
// CSR build (all 3 layers fused)
// ---------------------------------------------------------------------------
struct Csr3 {
    const int *src0, *dst0, *src1, *dst1, *src2, *dst2;
    int *cnt0, *cnt1, *cnt2;
    int *off0, *off1, *off2;
    int *cur0, *cur1, *cur2;
    int *eidx0, *eidx1, *eidx2;
    int *partial;   // [TILES] tile sums
    int *toff;      // [TILES] layer-relative exclusive tile offsets
};

__launch_bounds__(256)
__global__ void hist3(Csr3 c)
{
    int e = blockIdx.x * 256 + threadIdx.x;
    if (e < E0s) {
        atomicAdd(&c.cnt0[c.dst0[e]], 1);
    } else if (e < E0s + E1s) {
        atomicAdd(&c.cnt1[c.dst1[e - E0s]], 1);
    } else if (e < E0s + E1s + E2s) {
        atomicAdd(&c.cnt2[c.dst2[e - E0s - E1s]], 1);
    }
}

__launch_bounds__(256)
__global__ void fill3(Csr3 c)
{
    int e = blockIdx.x * 256 + threadIdx.x;
    if (e < E0s) {
        int p = atomicAdd(&c.cur0[c.dst0[e]], 1);
        c.eidx0[p] = c.src0[e];
    } else if (e < E0s + E1s) {
        int i = e - E0s;
        int p = atomicAdd(&c.cur1[c.dst1[i]], 1);
        c.eidx1[p] = c.src1[i];
    } else if (e < E0s + E1s + E2s) {
        int i = e - E0s - E1s;
        int p = atomicAdd(&c.cur2[c.dst2[i]], 1);
        c.eidx2[p] = c.src2[i];
    }
}

__device__ __forceinline__ void tile_map(int b, const Csr3& c,
                                         const int*& cnt, int*& off, int*& cur,
                                         int& base, int& n)
{
    if (b < T0)       { cnt = c.cnt0; off = c.off0; cur = c.cur0; base = b * TILE;        n = N1s; }
    else if (b < T0+T1){ cnt = c.cnt1; off = c.off1; cur = c.cur1; base = (b-T0) * TILE;   n = N2s; }
    else              { cnt = c.cnt2; off = c.off2; cur = c.cur2; base = (b-T0-T1) * TILE; n = N3s; }
}

// Phase A: per-tile sums (fully parallel, 34 blocks)
__launch_bounds__(256)
__global__ void scan_partial(Csr3 c)
{
    const int* cnt; int* off; int* cur; int base, n;
    tile_map(blockIdx.x, c, cnt, off, cur, base, n);

    const int t = threadIdx.x;
    int s = 0;
    #pragma unroll
    for (int j = 0; j < 8; ++j) {
        int i = base + t * 8 + j;
        if (i < n) s += cnt[i];
    }
    // wave butterfly reduce
    #pragma unroll
    for (int d = 1; d < 64; d <<= 1) s += __shfl_xor(s, d, 64);
    __shared__ int wsum[4];
    if ((t & 63) == 0) wsum[t >> 6] = s;
    __syncthreads();
    if (t == 0) c.partial[blockIdx.x] = wsum[0] + wsum[1] + wsum[2] + wsum[3];
}

// Phase B: one wave scans the 34 tile sums into layer-relative offsets,
// writes off[n] (= layer edge totals) for all three layers.
__launch_bounds__(64)
__global__ void scan_sums(Csr3 c)
{
    const int t = threadIdx.x;
    int v = (t < TILES) ? c.partial[t] : 0;
    int incl = v;
    #pragma unroll
    for (int d = 1; d < 64; d <<= 1) {
        int y = __shfl_up(incl, d, 64);
        if (t >= d) incl += y;
    }
    int excl = incl - v;
    int s1 = __shfl(excl, T0, 64);         // global prefix at layer1 start
    int s2 = __shfl(excl, T0 + T1, 64);    // global prefix at layer2 start
    int s3 = __shfl(incl, TILES - 1, 64);  // grand total
    int rel;
    if (t < T0)            rel = excl;
    else if (t < T0 + T1)  rel = excl - s1;
    else                   rel = excl - s2;
    if (t < TILES) c.toff[t] = rel;
    if (t == 0) {
        c.off0[N1s] = s1;
        c.off1[N2s] = s2 - s1;
        c.off2[N3s] = s3 - s2;
    }
}

// Phase C: per-tile block scan + apply offset (fully parallel, 34 blocks)
__launch_bounds__(256)
__global__ void scan_apply(Csr3 c)
{
    const int* cnt; int* off; int* cur; int base, n;
    tile_map(blockIdx.x, c, cnt, off, cur, base, n);

    const int t = threadIdx.x;
    const int lane = t & 63;
    const int wave = t >> 6;

    int v[8];
    int s = 0;
    #pragma unroll
    for (int j = 0; j < 8; ++j) {
        int i = base + t * 8 + j;
        int x = (i < n) ? cnt[i] : 0;
        v[j] = s;          // exclusive prefix within thread
        s += x;
    }
    // wave inclusive scan of thread sums
    int incl = s;
    #pragma unroll
    for (int d = 1; d < 64; d <<= 1) {
        int y = __shfl_up(incl, d, 64);
        if (lane >= d) incl += y;
    }
    int lexcl = incl - s;
    __shared__ int wsum[4];
    if (lane == 63) wsum[wave] = incl;
    __syncthreads();
    int wbase = 0;
    #pragma unroll
    for (int w = 0; w < 4; ++w) wbase += (w < wave) ? wsum[w] : 0;
    int tb = c.toff[blockIdx.x] + wbase + lexcl;
    #pragma unroll
    for (int j = 0; j < 8; ++j) {
        int i = base + t * 8 + j;
        if (i < n) { int o = tb + v[j]; off[i] = o; cur[i] = o; }
    }
}

// ---------------------------------------------------------------------------
// Gather + mean, fp32 source (layer 0, D=128), bf16 output.
// 32 threads/row, float4 per thread.
// ---------------------------------------------------------------------------
__launch_bounds__(256)
__global__ void gather_mean_f32(const float* __restrict__ X,
                                const int* __restrict__ eidx,
                                const int* __restrict__ off,
                                unsigned short* __restrict__ out,
                                int n_tgt)
{
    int gid = blockIdx.x * 256 + threadIdx.x;
    int row = gid >> 5;
    if (row >= n_tgt) return;
    int c = (gid & 31) << 2;

    int s = off[row];
    int e = off[row + 1];

    float a0 = 0.f, a1 = 0.f, a2 = 0.f, a3 = 0.f;
    int i = s;
    for (; i + 2 <= e; i += 2) {
        int s0 = eidx[i], s1 = eidx[i + 1];
        float4 v0 = *(const float4*)&X[(size_t)s0 * D_INs + c];
        float4 v1 = *(const float4*)&X[(size_t)s1 * D_INs + c];
        a0 += v0.x + v1.x; a1 += v0.y + v1.y;
        a2 += v0.z + v1.z; a3 += v0.w + v1.w;
    }
    if (i < e) {
        float4 v0 = *(const float4*)&X[(size_t)eidx[i] * D_INs + c];
        a0 += v0.x; a1 += v0.y; a2 += v0.z; a3 += v0.w;
    }
    float inv = 1.0f / fmaxf((float)(e - s), 1.0f);
    ushort4 o;
    o.x = f32_to_bf16_rne(a0 * inv);
    o.y = f32_to_bf16_rne(a1 * inv);
    o.z = f32_to_bf16_rne(a2 * inv);
    o.w = f32_to_bf16_rne(a3 * inv);
    *(ushort4*)&out[(size_t)row * D_INs + c] = o;
}

// ---------------------------------------------------------------------------
// Gather + mean, bf16 source (layers 1/2, D=256), bf16 output.
// 64 threads/row (one wave), ushort4 per thread.
// ---------------------------------------------------------------------------
__launch_bounds__(256)
__global__ void gather_mean_bf16(const unsigned short* __restrict__ X,
                                 const int* __restrict__ eidx,
                                 const int* __restrict__ off,
                                 unsigned short* __restrict__ out,
                                 int n_tgt)
{
    int gid = blockIdx.x * 256 + threadIdx.x;
    int row = gid >> 6;
    if (row >= n_tgt) return;
    int c = (gid & 63) << 2;

    int s = off[row];
    int e = off[row + 1];

    float a0 = 0.f, a1 = 0.f, a2 = 0.f, a3 = 0.f;
    int i = s;
    for (; i + 2 <= e; i += 2) {
        int s0 = eidx[i], s1 = eidx[i + 1];
        ushort4 v0 = *(const ushort4*)&X[(size_t)s0 * D_Hs + c];
        ushort4 v1 = *(const ushort4*)&X[(size_t)s1 * D_Hs + c];
        a0 += bf16_to_f32(v0.x) + bf16_to_f32(v1.x);
        a1 += bf16_to_f32(v0.y) + bf16_to_f32(v1.y);
        a2 += bf16_to_f32(v0.z) + bf16_to_f32(v1.z);
        a3 += bf16_to_f32(v0.w) + bf16_to_f32(v1.w);
    }
    if (i < e) {
        ushort4 v0 = *(const ushort4*)&X[(size_t)eidx[i] * D_Hs + c];
        a0 += bf16_to_f32(v0.x); a1 += bf16_to_f32(v0.y);
        a2 += bf16_to_f32(v0.z); a3 += bf16_to_f32(v0.w);
    }
    float inv = 1.0f / fmaxf((float)(e - s), 1.0f);
    ushort4 o;
    o.x = f32_to_bf16_rne(a0 * inv);
    o.y = f32_to_bf16_rne(a1 * inv);
    o.z = f32_to_bf16_rne(a2 * inv);
    o.w = f32_to_bf16_rne(a3 * inv);
    *(ushort4*)&out[(size_t)row * D_Hs + c] = o;
}

// ---------------------------------------------------------------------------
// bf16 MFMA dual-GEMM: C[M,N] = maybe_relu(A1@W1^T + A2@W2^T + bias)
// A1: bf16. A2: bf16 or fp32 (a2_f32) — cvt during staging.
// W1,W2: fp32, cvt during staging (L2-resident, tiny).
// 128x128 tile, 4 waves, v_mfma_f32_16x16x32_bf16, BK=32, LDS stride 40.
// ---------------------------------------------------------------------------
__launch_bounds__(256)
__global__ void mfma_gemm(const unsigned short* __restrict__ A1,
                          const void* __restrict__ A2v,
                          const float* __restrict__ W1f,
                          const float* __restrict__ W2f,
                          const float* __restrict__ bias,
                          void* __restrict__ Cout,
                          int M, int N, int K1, int K2,
                          int a2_f32, int relu, int out_bf16)
{
    __shared__ unsigned short As[128][40];
    __shared__ unsigned short Bs[128][40];

    const int tid  = threadIdx.x;
    const int wave = tid >> 6;
    const int lane = tid & 63;
    const int quad = lane >> 4;
    const int lr   = lane & 15;
    const int wm   = wave >> 1;
    const int wn   = wave & 1;
    const int row0 = blockIdx.x * 128;
    const int col0 = blockIdx.y * 128;

    floatx4 acc[4][4] = {};

    for (int seg = 0; seg < 2; ++seg) {
        const int K = (seg == 0) ? K1 : K2;
        const unsigned short* Ab = (seg == 0) ? A1 : (const unsigned short*)A2v;
        const float*          Af = (const float*)A2v;
        const float*          Wf = (seg == 0) ? W1f : W2f;
        const bool a_is_f32 = (seg == 1) && a2_f32;

        for (int k0 = 0; k0 < K; k0 += 32) {
            // stage A-tile (128 x 32)
            #pragma unroll
            for (int it = 0; it < 2; ++it) {
                int sid = tid + it * 256;
                int r = sid >> 2;
                int sc = (sid & 3) << 3;
                int gr = min(row0 + r, M - 1);
                if (a_is_f32) {
                    const float* p = &Af[(size_t)gr * K + k0 + sc];
                    float4 f0 = *(const float4*)p;
                    float4 f1 = *(const float4*)(p + 4);
                    ushort4 u0, u1;
                    u0.x = f32_to_bf16_rne(f0.x); u0.y = f32_to_bf16_rne(f0.y);
                    u0.z = f32_to_bf16_rne(f0.z); u0.w = f32_to_bf16_rne(f0.w);
                    u1.x = f32_to_bf16_rne(f1.x); u1.y = f32_to_bf16_rne(f1.y);
                    u1.z = f32_to_bf16_rne(f1.z); u1.w = f32_to_bf16_rne(f1.w);
                    *(ushort4*)&As[r][sc] = u0;
                    *(ushort4*)&As[r][sc + 4] = u1;
                } else {
                    uint4 v = *(const uint4*)&Ab[(size_t)gr * K + k0 + sc];
                    *(uint4*)&As[r][sc] = v;
                }
            }
            // stage W-tile (128 x 32) from fp32
            #pragma unroll
            for (int it = 0; it < 2; ++it) {
                int sid = tid + it * 256;
                int r = sid >> 2;
                int sc = (sid & 3) << 3;
                const float* p = &Wf[(size_t)(col0 + r) * K + k0 + sc];
                float4 f0 = *(const float4*)p;
                float4 f1 = *(const float4*)(p + 4);
                ushort4 u0, u1;
                u0.x = f32_to_bf16_rne(f0.x); u0.y = f32_to_bf16_rne(f0.y);
                u0.z = f32_to_bf16_rne(f0.z); u0.w = f32_to_bf16_rne(f0.w);
                u1.x = f32_to_bf16_rne(f1.x); u1.y = f32_to_bf16_rne(f1.y);
                u1.z = f32_to_bf16_rne(f1.z); u1.w = f32_to_bf16_rne(f1.w);
                *(ushort4*)&Bs[r][sc] = u0;
                *(ushort4*)&Bs[r][sc + 4] = u1;
            }
            __syncthreads();

            short8 afr[4], bfr[4];
            #pragma unroll
            for (int mt = 0; mt < 4; ++mt)
                afr[mt] = *(const short8*)&As[wm * 64 + mt * 16 + lr][quad * 8];
            #pragma unroll
            for (int nt = 0; nt < 4; ++nt)
                bfr[nt] = *(const short8*)&Bs[wn * 64 + nt * 16 + lr][quad * 8];

            #pragma unroll
            for (int mt = 0; mt < 4; ++mt)
                #pragma unroll
                for (int nt = 0; nt < 4; ++nt)
                    acc[mt][nt] = __builtin_amdgcn_mfma_f32_16x16x32_bf16(
                        afr[mt], bfr[nt], acc[mt][nt], 0, 0, 0);

            __syncthreads();
        }
    }

    // epilogue: row = quad*4 + reg, col = lr (m89-verified C/D layout)
    #pragma unroll
    for (int nt = 0; nt < 4; ++nt) {
        int gc = col0 + wn * 64 + nt * 16 + lr;
        float bv = bias[gc];
        #pragma unroll
        for (int mt = 0; mt < 4; ++mt) {
            #pragma unroll
            for (int reg = 0; reg < 4; ++reg) {
                int gr = row0 + wm * 64 + mt * 16 + quad * 4 + reg;
                if (gr < M) {
                    float v = acc[mt][nt][reg] + bv;
                    if (relu) v = fmaxf(v, 0.f);
                    if (out_bf16)
                        ((unsigned short*)Cout)[(size_t)gr * N + gc] = f32_to_bf16_rne(v);
                    else
                        ((float*)Cout)[(size_t)gr * N + gc] = v;
                }
            }
        }
    }
}

// ---------------------------------------------------------------------------
// launch
// ---------------------------------------------------------------------------
extern "C" void kernel_launch(void* const* d_in, const int* in_sizes, int n_in,
                              void* d_out, int out_size, void* d_ws, size_t ws_size,
                              hipStream_t stream)
{
    const float* x   = (const float*)d_in[0];
    const int* src0  = (const int*)d_in[1];
    const int* dst0  = (const int*)d_in[2];
    const int* src1  = (const int*)d_in[3];
    const int* dst1  = (const int*)d_in[4];
    const int* src2  = (const int*)d_in[5];
    const int* dst2  = (const int*)d_in[6];
    const float* wl0 = (const float*)d_in[7];
    const float* wr0 = (const float*)d_in[8];
    const float* b0  = (const float*)d_in[9];
    const float* wl1 = (const float*)d_in[10];
    const float* wr1 = (const float*)d_in[11];
    const float* b1  = (const float*)d_in[12];
    const float* wl2 = (const float*)d_in[13];
    const float* wr2 = (const float*)d_in[14];
    const float* b2  = (const float*)d_in[15];

    // Workspace layout
    unsigned short* ws = (unsigned short*)d_ws;
    unsigned short* h1    = ws;                                 // 12,800,000 shorts
    unsigned short* h2    = h1 + (size_t)N1s * D_Hs;            //  3,200,000
    unsigned short* meanA = h2 + (size_t)N2s * D_Hs;            //  6,400,000 (reused per layer)
    int* ib = (int*)(meanA + (size_t)N1s * D_INs);
    int* cnt0 = ib;                          // 50048  (cnt block is memset together)
    int* cnt1 = cnt0 + 50048;                // 12544
    int* cnt2 = cnt1 + 12544;                // 3264
    int* off0 = cnt2 + 3264;                 // 50056
    int* off1 = off0 + 50056;                // 12544
    int* off2 = off1 + 12544;                // 3264
    int* cur0 = off2 + 3264;                 // 50048
    int* cur1 = cur0 + 50048;                // 12544
    int* cur2 = cur1 + 12544;                // 3264
    int* eidx0 = cur2 + 3264;                // 500000
    int* eidx1 = eidx0 + 500000;             // 125000
    int* eidx2 = eidx1 + 125000;             // 32000
    int* partial = eidx2 + 32000;            // 64
    int* toff    = partial + 64;             // 64

    Csr3 c;
    c.src0 = src0; c.dst0 = dst0; c.src1 = src1; c.dst1 = dst1;
    c.src2 = src2; c.dst2 = dst2;
    c.cnt0 = cnt0; c.cnt1 = cnt1; c.cnt2 = cnt2;
    c.off0 = off0; c.off1 = off1; c.off2 = off2;
    c.cur0 = cur0; c.cur1 = cur1; c.cur2 = cur2;
    c.eidx0 = eidx0; c.eidx1 = eidx1; c.eidx2 = eidx2;
    c.partial = partial; c.toff = toff;

    // --- CSR build for all 3 layers ---
    hipMemsetAsync(cnt0, 0, (50048 + 12544 + 3264) * sizeof(int), stream);
    const int Etot = E0s + E1s + E2s;
    hist3<<<(Etot + 255) / 256, 256, 0, stream>>>(c);
    scan_partial<<<TILES, 256, 0, stream>>>(c);
    scan_sums<<<1, 64, 0, stream>>>(c);
    scan_apply<<<TILES, 256, 0, stream>>>(c);
    fill3<<<(Etot + 255) / 256, 256, 0, stream>>>(c);

    // ---- layer 0: x (N0,128 fp32) -> h1 (N1,256 bf16), relu ----
    {
        int th = N1s * 32;
        gather_mean_f32<<<(th + 255) / 256, 256, 0, stream>>>(x, eidx0, off0,
                                                              meanA, N1s);
        dim3 g((N1s + 127) / 128, D_Hs / 128);
        mfma_gemm<<<g, 256, 0, stream>>>(meanA, x, wl0, wr0, b0, h1,
                                         N1s, D_Hs, D_INs, D_INs, 1, 1, 1);
    }
    // ---- layer 1: h1 (N1,256) -> h2 (N2,256 bf16), relu ----
    {
        int th = N2s * 64;
        gather_mean_bf16<<<(th + 255) / 256, 256, 0, stream>>>(h1, eidx1, off1,
                                                               meanA, N2s);
        dim3 g((N2s + 127) / 128, D_Hs / 128);
        mfma_gemm<<<g, 256, 0, stream>>>(meanA, h1, wl1, wr1, b1, h2,
                                         N2s, D_Hs, D_Hs, D_Hs, 0, 1, 1);
    }
    // ---- layer 2: h2 (N2,256) -> out (N3,128 fp32) ----
    {
        int th = N3s * 64;
        gather_mean_bf16<<<(th + 255) / 256, 256, 0, stream>>>(h2, eidx2, off2,
                                                               meanA, N3s);
        dim3 g((N3s + 127) / 128, D_OUTs / 128);
        mfma_gemm<<<g, 256, 0, stream>>>(meanA, h2, wl2, wr2, b2, (float*)d_out,
                                         N3s, D_OUTs, D_Hs, D_Hs, 0, 0, 0);
    }
}